// Round 11
// baseline (122.661 us; speedup 1.0000x reference)
//
#include <hip/hip_runtime.h>
#include <hip/hip_bf16.h>
#include <hip/hip_fp16.h>
#include <math.h>

#define NNODES 50000
#define KNEI 16

typedef __attribute__((ext_vector_type(8))) short bf8;
typedef __attribute__((ext_vector_type(4))) float f32x4;

static __device__ __forceinline__ unsigned short f2bf(float f) {
    __hip_bfloat16 h = __float2bfloat16(f);
    return *reinterpret_cast<unsigned short*>(&h);
}
static __device__ __forceinline__ unsigned short f2h(float f) {
    __half h = __float2half(f);
    return *reinterpret_cast<unsigned short*>(&h);
}
static __device__ __forceinline__ float2 h2f2(unsigned int u) {
    __half2 h = *reinterpret_cast<__half2*>(&u);
    return __half22float2(h);
}

// ---------------------------------------------------------------------------
// prep_bt: BT[c][k] = bf16(Wc[k][c]), c in 0..255, k in 0..127 (64 KB).
// Wc[k][c] = c<128 ? W[k][c] - W[k+128][c] : W[k+128][c-128]
// ---------------------------------------------------------------------------
__global__ __launch_bounds__(128) void prep_bt(const float* __restrict__ W,
                                               unsigned short* __restrict__ BT) {
    int c = blockIdx.x;      // 0..255
    int k = threadIdx.x;     // 0..127
    float v;
    if (c < 128) v = W[k * 128 + c] - W[(k + 128) * 128 + c];
    else         v = W[(k + 128) * 128 + (c - 128)];
    BT[c * 128 + k] = f2bf(v);
}

// ---------------------------------------------------------------------------
// gemm_bf16: R = x (50000x128) @ Wc (128x256) via mfma_f32_16x16x32_bf16.
// FUSED column tiles: one block = 64 rows x ALL 256 cols (x staged ONCE).
// 4 waves; wave w owns cols [64w, 64w+64) = 4 n-frags; 4 m-frags; 64 MFMA/wave.
// Cols <128 -> Ph (+bias), >=128 -> Qh (both fp16).
// Epilogue: acc -> fp16 -> LDS repack [64][264] -> coalesced uint4 stores.
// ---------------------------------------------------------------------------
__global__ __launch_bounds__(256) void gemm_bf16(const float* __restrict__ x,
                                                 const unsigned short* __restrict__ BT,
                                                 const float* __restrict__ bias,
                                                 unsigned short* __restrict__ Ph,
                                                 unsigned short* __restrict__ Qh) {
    __shared__ unsigned short Ls[64 * 264];   // 33.8 KB; staging uses stride 136
    const int t = threadIdx.x;
    const int row0 = blockIdx.x * 64;

    // stage + convert: 64x128 fp32 -> bf16 (stride-136 layout), 8 float4/thread
    #pragma unroll
    for (int i = 0; i < 8; ++i) {
        int f  = t + i * 256;          // 0..2047
        int r  = f >> 5;
        int c4 = f & 31;
        int gr = row0 + r;
        float4 v = make_float4(0.f, 0.f, 0.f, 0.f);
        if (gr < NNODES) v = ((const float4*)x)[gr * 32 + c4];
        unsigned int u0 = (unsigned int)f2bf(v.x) | ((unsigned int)f2bf(v.y) << 16);
        unsigned int u1 = (unsigned int)f2bf(v.z) | ((unsigned int)f2bf(v.w) << 16);
        *(uint2*)&Ls[r * 136 + c4 * 4] = make_uint2(u0, u1);
    }
    __syncthreads();

    const int w  = t >> 6;          // wave 0..3
    const int l  = t & 63;          // lane
    const int lr = l & 15;          // row/col within frag
    const int lk = (l >> 4) * 8;    // k-offset within frag

    f32x4 acc[4][4];
    #pragma unroll
    for (int m = 0; m < 4; ++m)
        #pragma unroll
        for (int n = 0; n < 4; ++n) acc[m][n] = (f32x4){0.f, 0.f, 0.f, 0.f};

    const int colG0 = w * 64 + lr;               // global col of n-frag 0
    const unsigned short* bt0 = BT + colG0 * 128 + lk;

    #pragma unroll
    for (int s = 0; s < 4; ++s) {
        const int kp = s * 32;
        bf8 a[4], b[4];
        #pragma unroll
        for (int m = 0; m < 4; ++m)
            a[m] = *(const bf8*)&Ls[(m * 16 + lr) * 136 + kp + lk];
        #pragma unroll
        for (int n = 0; n < 4; ++n)
            b[n] = *(const bf8*)(bt0 + n * 16 * 128 + kp);
        #pragma unroll
        for (int m = 0; m < 4; ++m)
            #pragma unroll
            for (int n = 0; n < 4; ++n)
                acc[m][n] = __builtin_amdgcn_mfma_f32_16x16x32_bf16(a[m], b[n], acc[m][n], 0, 0, 0);
    }

    // bias per n-frag (cols <128 only; wave-uniform P/Q split per (w,n))
    float bb[4];
    #pragma unroll
    for (int n = 0; n < 4; ++n) {
        int col = colG0 + n * 16;
        bb[n] = (col < 128) ? bias[col] : 0.f;
    }

    __syncthreads();                 // staging reads done before repack reuse
    // repack: D layout col=lane&15, row=(lane>>4)*4+reg (m89-verified)
    #pragma unroll
    for (int m = 0; m < 4; ++m) {
        #pragma unroll
        for (int n = 0; n < 4; ++n) {
            int cg = colG0 + n * 16;
            #pragma unroll
            for (int i = 0; i < 4; ++i) {
                int rl = m * 16 + (l >> 4) * 4 + i;
                Ls[rl * 264 + cg] = f2h(acc[m][n][i] + bb[n]);
            }
        }
    }
    __syncthreads();

    // coalesced store-out: 64 rows x 32 uint4-segments (256 cols)
    #pragma unroll
    for (int it = 0; it < 8; ++it) {
        int cidx = t + it * 256;     // 0..2047
        int row  = cidx >> 5;
        int seg  = cidx & 31;        // seg*8 = col in 0..255
        uint4 v = *(const uint4*)&Ls[row * 264 + seg * 8];
        int gr = row0 + row;
        if (gr < NNODES) {
            int col = seg * 8;
            if (col < 128)
                *(uint4*)(Ph + (size_t)gr * 128 + col) = v;
            else
                *(uint4*)(Qh + (size_t)gr * 128 + (col - 128)) = v;
        }
    }
}

// ---------------------------------------------------------------------------
// gather_max: out[n,o] = elu(P[n,o] + max_valid_k Q[edge[n,k],o])  (ELU monotone)
// fp16 P/Q. 16 nodes/block, 16 thr/node, 8 halves (uint4) per thread.
// All 16 gathers issued first (MLP=16); masked k substitutes always-valid e[0].
// ---------------------------------------------------------------------------
__global__ __launch_bounds__(256) void gather_max(const unsigned short* __restrict__ Ph,
                                                  const unsigned short* __restrict__ Qh,
                                                  const int* __restrict__ edge,
                                                  float* __restrict__ out) {
    const int t  = threadIdx.x;
    const int n  = blockIdx.x * 16 + (t >> 4);   // 50000 = 16 * 3125
    const int o8 = (t & 15) * 8;

    const int4* er = (const int4*)(edge + n * KNEI);
    int4 e0 = er[0], e1 = er[1], e2 = er[2], e3 = er[3];
    int ia[16] = {e0.x, e0.y, e0.z, e0.w, e1.x, e1.y, e1.z, e1.w,
                  e2.x, e2.y, e2.z, e2.w, e3.x, e3.y, e3.z, e3.w};
    const int s0 = ia[0];                        // k=0 never masked
    const unsigned short* qb = Qh + o8;

    uint4 q[16];
    #pragma unroll
    for (int k = 0; k < 16; ++k) {
        int ix = ia[k] < 0 ? s0 : ia[k];
        q[k] = *(const uint4*)(qb + (size_t)ix * 128);
    }
    uint4 pv = *(const uint4*)(Ph + (size_t)n * 128 + o8);

    float2 m0 = h2f2(q[0].x), m1 = h2f2(q[0].y), m2 = h2f2(q[0].z), m3 = h2f2(q[0].w);
    #pragma unroll
    for (int k = 1; k < 16; ++k) {
        float2 a0 = h2f2(q[k].x), a1 = h2f2(q[k].y), a2 = h2f2(q[k].z), a3 = h2f2(q[k].w);
        m0.x = fmaxf(m0.x, a0.x); m0.y = fmaxf(m0.y, a0.y);
        m1.x = fmaxf(m1.x, a1.x); m1.y = fmaxf(m1.y, a1.y);
        m2.x = fmaxf(m2.x, a2.x); m2.y = fmaxf(m2.y, a2.y);
        m3.x = fmaxf(m3.x, a3.x); m3.y = fmaxf(m3.y, a3.y);
    }
    float2 p0 = h2f2(pv.x), p1 = h2f2(pv.y), p2 = h2f2(pv.z), p3 = h2f2(pv.w);

    float z[8] = {p0.x + m0.x, p0.y + m0.y, p1.x + m1.x, p1.y + m1.y,
                  p2.x + m2.x, p2.y + m2.y, p3.x + m3.x, p3.y + m3.y};
    float r[8];
    #pragma unroll
    for (int i = 0; i < 8; ++i) r[i] = z[i] > 0.f ? z[i] : expm1f(z[i]);

    float* ob = out + (size_t)n * 128 + o8;
    *(float4*)ob       = make_float4(r[0], r[1], r[2], r[3]);
    *(float4*)(ob + 4) = make_float4(r[4], r[5], r[6], r[7]);
}

extern "C" void kernel_launch(void* const* d_in, const int* in_sizes, int n_in,
                              void* d_out, int out_size, void* d_ws, size_t ws_size,
                              hipStream_t stream) {
    const float* x    = (const float*)d_in[0];
    const int*   edge = (const int*)d_in[1];
    const float* W    = (const float*)d_in[2];
    const float* bias = (const float*)d_in[3];
    float* out = (float*)d_out;

    unsigned short* Qh = (unsigned short*)d_ws;              // 12.8 MB
    unsigned short* Ph = Qh + 6400000;                       // 12.8 MB
    unsigned short* BT = Qh + 12800000;                      // 64 KB

    prep_bt<<<256, 128, 0, stream>>>(W, BT);
    gemm_bf16<<<(NNODES + 63) / 64, 256, 0, stream>>>(x, BT, bias, Ph, Qh);
    gather_max<<<NNODES / 16, 256, 0, stream>>>(Ph, Qh, edge, out);
}

// Round 13
// 119.480 us; speedup vs baseline: 1.0266x; 1.0266x over previous
//
#include <hip/hip_runtime.h>
#include <hip/hip_bf16.h>
#include <hip/hip_fp16.h>
#include <math.h>

#define NNODES 50000
#define KNEI 16
#define GBLK 391   // persistent gemm blocks; 2 tiles (of 782) each

typedef __attribute__((ext_vector_type(8))) short bf8;
typedef __attribute__((ext_vector_type(4))) float f32x4;

static __device__ __forceinline__ unsigned short f2bf(float f) {
    __hip_bfloat16 h = __float2bfloat16(f);
    return *reinterpret_cast<unsigned short*>(&h);
}
static __device__ __forceinline__ unsigned short f2h(float f) {
    __half h = __float2half(f);
    return *reinterpret_cast<unsigned short*>(&h);
}
static __device__ __forceinline__ float2 h2f2(unsigned int u) {
    __half2 h = *reinterpret_cast<__half2*>(&u);
    return __half22float2(h);
}

// ---------------------------------------------------------------------------
// prep_bt: BT[c][k] = bf16(Wc[k][c]), c in 0..255, k in 0..127 (64 KB).
// Wc[k][c] = c<128 ? W[k][c] - W[k+128][c] : W[k+128][c-128]
// ---------------------------------------------------------------------------
__global__ __launch_bounds__(128) void prep_bt(const float* __restrict__ W,
                                               unsigned short* __restrict__ BT) {
    int c = blockIdx.x;      // 0..255
    int k = threadIdx.x;     // 0..127
    float v;
    if (c < 128) v = W[k * 128 + c] - W[(k + 128) * 128 + c];
    else         v = W[(k + 128) * 128 + (c - 128)];
    BT[c * 128 + k] = f2bf(v);
}

// ---------------------------------------------------------------------------
// gemm_bf16 (persistent, software-pipelined):
// 391 blocks x 256 thr (4 waves); block b does tiles {b, b+391} of 64 rows.
// Pipeline: convert regs->LDS, ISSUE next tile's global loads into regs,
// then MFMA + direct fp16 scalar store epilogue (no LDS repack).
// Wave w owns cols [64w, 64w+64): w<2 -> Ph (+bias), w>=2 -> Qh.
// Store pattern: per (w,n) 16 lanes write 32 contiguous B; 4 n-frags/wave
// cover the full 128-B line of each row -> L2 write-combines.
// ---------------------------------------------------------------------------
__global__ __launch_bounds__(256) void gemm_bf16(const float* __restrict__ x,
                                                 const unsigned short* __restrict__ BT,
                                                 const float* __restrict__ bias,
                                                 unsigned short* __restrict__ Ph,
                                                 unsigned short* __restrict__ Qh) {
    __shared__ unsigned short S[64 * 136];    // 17.4 KB staging (bf16, pad 136)
    const int t  = threadIdx.x;
    const int w  = t >> 6;          // wave 0..3
    const int l  = t & 63;          // lane
    const int lr = l & 15;          // row/col within frag
    const int lk = (l >> 4) * 8;    // k-offset within frag
    const int colG0 = w * 64 + lr;  // global col of n-frag 0
    const unsigned short* bt0 = BT + colG0 * 128 + lk;

    float bb[4];
    #pragma unroll
    for (int n = 0; n < 4; ++n) {
        int col = colG0 + n * 16;
        bb[n] = (col < 128) ? bias[col] : 0.f;
    }

    int tile = blockIdx.x;

    // prologue: load tile 0's x rows into registers
    float4 R[8];
    {
        const int row0 = tile * 64;
        #pragma unroll
        for (int i = 0; i < 8; ++i) {
            int f  = t + i * 256;
            int r  = f >> 5;
            int c4 = f & 31;
            int gr = row0 + r;
            R[i] = (gr < NNODES) ? ((const float4*)x)[gr * 32 + c4]
                                 : make_float4(0.f, 0.f, 0.f, 0.f);
        }
    }

    #pragma unroll
    for (int it = 0; it < 2; ++it) {
        const int row0 = tile * 64;

        __syncthreads();            // prior iteration's S readers done
        // stage: convert regs -> LDS bf16
        #pragma unroll
        for (int i = 0; i < 8; ++i) {
            int f  = t + i * 256;
            int r  = f >> 5;
            int c4 = f & 31;
            unsigned int u0 = (unsigned int)f2bf(R[i].x) | ((unsigned int)f2bf(R[i].y) << 16);
            unsigned int u1 = (unsigned int)f2bf(R[i].z) | ((unsigned int)f2bf(R[i].w) << 16);
            *(uint2*)&S[r * 136 + c4 * 4] = make_uint2(u0, u1);
        }
        // prefetch next tile's x into regs (in flight during MFMA + stores)
        if (it == 0) {
            const int prow0 = (tile + GBLK) * 64;
            #pragma unroll
            for (int i = 0; i < 8; ++i) {
                int f  = t + i * 256;
                int r  = f >> 5;
                int c4 = f & 31;
                int gr = prow0 + r;
                R[i] = (gr < NNODES) ? ((const float4*)x)[gr * 32 + c4]
                                     : make_float4(0.f, 0.f, 0.f, 0.f);
            }
        }
        __syncthreads();            // S ready

        f32x4 acc[4][4];
        #pragma unroll
        for (int m = 0; m < 4; ++m)
            #pragma unroll
            for (int n = 0; n < 4; ++n) acc[m][n] = (f32x4){0.f, 0.f, 0.f, 0.f};

        #pragma unroll
        for (int s = 0; s < 4; ++s) {
            const int kp = s * 32;
            bf8 a[4], b[4];
            #pragma unroll
            for (int m = 0; m < 4; ++m)
                a[m] = *(const bf8*)&S[(m * 16 + lr) * 136 + kp + lk];
            #pragma unroll
            for (int n = 0; n < 4; ++n)
                b[n] = *(const bf8*)(bt0 + n * 16 * 128 + kp);
            #pragma unroll
            for (int m = 0; m < 4; ++m)
                #pragma unroll
                for (int n = 0; n < 4; ++n)
                    acc[m][n] = __builtin_amdgcn_mfma_f32_16x16x32_bf16(a[m], b[n], acc[m][n], 0, 0, 0);
        }

        // epilogue: direct scalar fp16 stores (D layout: col=lane&15,
        // row=(lane>>4)*4+reg; m89-verified)
        #pragma unroll
        for (int m = 0; m < 4; ++m) {
            #pragma unroll
            for (int n = 0; n < 4; ++n) {
                const int col = colG0 + n * 16;
                unsigned short* base = (col < 128) ? (Ph + col) : (Qh + (col - 128));
                #pragma unroll
                for (int i = 0; i < 4; ++i) {
                    int row = row0 + m * 16 + (l >> 4) * 4 + i;
                    if (row < NNODES)
                        base[(size_t)row * 128] = f2h(acc[m][n][i] + bb[n]);
                }
            }
        }
        tile += GBLK;
    }
}

// ---------------------------------------------------------------------------
// gather_max: out[n,o] = elu(P[n,o] + max_valid_k Q[edge[n,k],o])  (ELU monotone)
// fp16 P/Q. 16 nodes/block, 16 thr/node, 8 halves (uint4) per thread.
// All 16 gathers issued first (MLP=16); masked k substitutes always-valid e[0].
// ---------------------------------------------------------------------------
__global__ __launch_bounds__(256) void gather_max(const unsigned short* __restrict__ Ph,
                                                  const unsigned short* __restrict__ Qh,
                                                  const int* __restrict__ edge,
                                                  float* __restrict__ out) {
    const int t  = threadIdx.x;
    const int n  = blockIdx.x * 16 + (t >> 4);   // 50000 = 16 * 3125
    const int o8 = (t & 15) * 8;

    const int4* er = (const int4*)(edge + n * KNEI);
    int4 e0 = er[0], e1 = er[1], e2 = er[2], e3 = er[3];
    int ia[16] = {e0.x, e0.y, e0.z, e0.w, e1.x, e1.y, e1.z, e1.w,
                  e2.x, e2.y, e2.z, e2.w, e3.x, e3.y, e3.z, e3.w};
    const int s0 = ia[0];                        // k=0 never masked
    const unsigned short* qb = Qh + o8;

    uint4 q[16];
    #pragma unroll
    for (int k = 0; k < 16; ++k) {
        int ix = ia[k] < 0 ? s0 : ia[k];
        q[k] = *(const uint4*)(qb + (size_t)ix * 128);
    }
    uint4 pv = *(const uint4*)(Ph + (size_t)n * 128 + o8);

    float2 m0 = h2f2(q[0].x), m1 = h2f2(q[0].y), m2 = h2f2(q[0].z), m3 = h2f2(q[0].w);
    #pragma unroll
    for (int k = 1; k < 16; ++k) {
        float2 a0 = h2f2(q[k].x), a1 = h2f2(q[k].y), a2 = h2f2(q[k].z), a3 = h2f2(q[k].w);
        m0.x = fmaxf(m0.x, a0.x); m0.y = fmaxf(m0.y, a0.y);
        m1.x = fmaxf(m1.x, a1.x); m1.y = fmaxf(m1.y, a1.y);
        m2.x = fmaxf(m2.x, a2.x); m2.y = fmaxf(m2.y, a2.y);
        m3.x = fmaxf(m3.x, a3.x); m3.y = fmaxf(m3.y, a3.y);
    }
    float2 p0 = h2f2(pv.x), p1 = h2f2(pv.y), p2 = h2f2(pv.z), p3 = h2f2(pv.w);

    float z[8] = {p0.x + m0.x, p0.y + m0.y, p1.x + m1.x, p1.y + m1.y,
                  p2.x + m2.x, p2.y + m2.y, p3.x + m3.x, p3.y + m3.y};
    float r[8];
    #pragma unroll
    for (int i = 0; i < 8; ++i) r[i] = z[i] > 0.f ? z[i] : expm1f(z[i]);

    float* ob = out + (size_t)n * 128 + o8;
    *(float4*)ob       = make_float4(r[0], r[1], r[2], r[3]);
    *(float4*)(ob + 4) = make_float4(r[4], r[5], r[6], r[7]);
}

extern "C" void kernel_launch(void* const* d_in, const int* in_sizes, int n_in,
                              void* d_out, int out_size, void* d_ws, size_t ws_size,
                              hipStream_t stream) {
    const float* x    = (const float*)d_in[0];
    const int*   edge = (const int*)d_in[1];
    const float* W    = (const float*)d_in[2];
    const float* bias = (const float*)d_in[3];
    float* out = (float*)d_out;

    unsigned short* Qh = (unsigned short*)d_ws;              // 12.8 MB
    unsigned short* Ph = Qh + 6400000;                       // 12.8 MB
    unsigned short* BT = Qh + 12800000;                      // 64 KB

    prep_bt<<<256, 128, 0, stream>>>(W, BT);
    gemm_bf16<<<GBLK, 256, 0, stream>>>(x, BT, bias, Ph, Qh);
    gather_max<<<NNODES / 16, 256, 0, stream>>>(Ph, Qh, edge, out);
}